// Round 5
// baseline (96.229 us; speedup 1.0000x reference)
//
#include <hip/hip_runtime.h>

// N=16, C_X=512, C_W=32, groups=16, H=W=out_h=out_w=64, K=3, PAD=1.
constexpr int NB   = 16;
constexpr int CX   = 512;
constexpr int CW   = 32;
constexpr int GRP  = 16;   // CX / CW
constexpr int HW   = 64;
constexpr int PIX  = HW * HW; // 4096

// NO group loop: one thread per (n, c, g, oh, ow-pair). Block = 512 threads
// = one (n,c,oh) row x all 16 groups. Weights for the row staged once in LDS
// (9x64 floats = 2.3 KB), read by all 16 groups. Every thread: 3 independent
// dwordx2 input loads + 9 LDS reads + 6 shfl + 18 FMA + 1 dwordx2 store.
// All latency hiding via TLP (threads fully independent).
__global__ __launch_bounds__(512, 8) void agg_kernel(
    const float* __restrict__ in,   // [16][512][64][64]
    const float* __restrict__ wt,   // [16][32][9][4096]
    float* __restrict__ out)        // [16][512][64][64]
{
    __shared__ float wlds[9][64];

    // Chunked XCD swizzle: 32768 blocks, 32768 % 8 == 0 -> bijective.
    // Consecutive wg (consecutive oh, sharing input rows) stay on one XCD.
    int bid = blockIdx.x;
    int wg  = (bid & 7) * (32768 / 8) + (bid >> 3);

    int oh = wg & 63;
    int c  = (wg >> 6) & 31;
    int n  = wg >> 11;

    int tid  = threadIdx.x;
    int pair = tid & 31;   // ow pair: covers pixels x=2*pair, 2*pair+1
    int g    = tid >> 5;   // group 0..15

    // ---- Stage this row's weights: wlds[kk][col] = wt[n][c][kk][oh*64+col].
    const float* wbase = wt + ((size_t)(n * CW + c) * 9) * PIX + oh * HW;
    if (tid < 288) {
        int f   = tid * 2;        // flat index into [9][64]
        int kk  = f >> 6;
        int col = f & 63;
        float2 v = *(const float2*)(wbase + kk * PIX + col);
        *(float2*)(&wlds[0][0] + f) = v;
    }
    __syncthreads();

    int x = pair * 2;

    // Zero-pad masks (also kill cross-boundary shuffle garbage: pair==0 is
    // the first lane of each 32-lane half, pair==31 the last).
    float mt = (oh == 0)    ? 0.f : 1.f;
    float mb = (oh == 63)   ? 0.f : 1.f;
    float ml = (pair == 0)  ? 0.f : 1.f;
    float mr = (pair == 31) ? 0.f : 1.f;

    const int r0 = (oh == 0  ? 0  : oh - 1) * HW;
    const int r1 = oh * HW;
    const int r2 = (oh == 63 ? 63 : oh + 1) * HW;

    const float* ip = in + ((size_t)(n * CX) + (size_t)(g * CW + c)) * PIX;

    float2 q0 = *(const float2*)(ip + r0 + x);
    float2 q1 = *(const float2*)(ip + r1 + x);
    float2 q2 = *(const float2*)(ip + r2 + x);

    // Halo pixels from neighbor lanes.
    float l0 = __shfl_up(q0.y, 1), h0 = __shfl_down(q0.x, 1);
    float l1 = __shfl_up(q1.y, 1), h1 = __shfl_down(q1.x, 1);
    float l2 = __shfl_up(q2.y, 1), h2 = __shfl_down(q2.x, 1);

    float2 w0 = *(const float2*)&wlds[0][x];
    float2 w1 = *(const float2*)&wlds[1][x];
    float2 w2 = *(const float2*)&wlds[2][x];
    float2 w3 = *(const float2*)&wlds[3][x];
    float2 w4 = *(const float2*)&wlds[4][x];
    float2 w5 = *(const float2*)&wlds[5][x];
    float2 w6 = *(const float2*)&wlds[6][x];
    float2 w7 = *(const float2*)&wlds[7][x];
    float2 w8 = *(const float2*)&wlds[8][x];

    // Fold the zero-pad masks into the weights.
    w0.x *= ml * mt; w0.y *= mt;
    w1.x *= mt;      w1.y *= mt;
    w2.x *= mt;      w2.y *= mt * mr;
    w3.x *= ml;
    w5.y *= mr;
    w6.x *= ml * mb; w6.y *= mb;
    w7.x *= mb;      w7.y *= mb;
    w8.x *= mb;      w8.y *= mb * mr;

    float ax, ay;
    ax = w0.x * l0;              ay = w0.y * q0.x;
    ax = fmaf(w1.x, q0.x, ax);   ay = fmaf(w1.y, q0.y, ay);
    ax = fmaf(w2.x, q0.y, ax);   ay = fmaf(w2.y, h0,   ay);
    ax = fmaf(w3.x, l1,   ax);   ay = fmaf(w3.y, q1.x, ay);
    ax = fmaf(w4.x, q1.x, ax);   ay = fmaf(w4.y, q1.y, ay);
    ax = fmaf(w5.x, q1.y, ax);   ay = fmaf(w5.y, h1,   ay);
    ax = fmaf(w6.x, l2,   ax);   ay = fmaf(w6.y, q2.x, ay);
    ax = fmaf(w7.x, q2.x, ax);   ay = fmaf(w7.y, q2.y, ay);
    ax = fmaf(w8.x, q2.y, ax);   ay = fmaf(w8.y, h2,   ay);

    float* op = out + ((size_t)(n * CX) + (size_t)(g * CW + c)) * PIX + r1 + x;
    *(float2*)op = float2{ax, ay};
}

extern "C" void kernel_launch(void* const* d_in, const int* in_sizes, int n_in,
                              void* d_out, int out_size, void* d_ws, size_t ws_size,
                              hipStream_t stream) {
    const float* in = (const float*)d_in[0];   // (16, 512, 64, 64) f32
    const float* wt = (const float*)d_in[1];   // (16, 32, 9, 4096) f32
    float* out = (float*)d_out;                // (16, 512, 64, 64) f32

    const int grid  = NB * CW * HW;   // 32768 blocks
    const int block = 512;            // 16 groups x 32 pairs
    agg_kernel<<<grid, block, 0, stream>>>(in, wt, out);
}

// Round 6
// 74.238 us; speedup vs baseline: 1.2962x; 1.2962x over previous
//
#include <hip/hip_runtime.h>

// N=16, C_X=512, C_W=32, groups=16, H=W=out_h=out_w=64, K=3, PAD=1.
constexpr int NB   = 16;
constexpr int CX   = 512;
constexpr int CW   = 32;
constexpr int GRP  = 16;   // CX / CW
constexpr int HW   = 64;
constexpr int PIX  = HW * HW; // 4096

// One-shot threads, float4 width: thread <-> (n, c, g, oh, quad of 4 ow).
// Block = 256 threads = one (n,c,oh) row x all 16 groups x 16 quads.
// Per thread: 3 independent dwordx4 input loads + 9 LDS float4 weight reads
// (broadcast across groups) + 6 shfl halos + 36 FMA + 1 dwordx4 store.
__global__ __launch_bounds__(256, 8) void agg_kernel(
    const float* __restrict__ in,   // [16][512][64][64]
    const float* __restrict__ wt,   // [16][32][9][4096]
    float* __restrict__ out)        // [16][512][64][64]
{
    __shared__ float wlds[9][64];

    // Chunked XCD swizzle: 32768 blocks, bijective (32768 % 8 == 0).
    // Consecutive wg (consecutive oh, sharing input rows) stay on one XCD.
    int bid = blockIdx.x;
    int wg  = (bid & 7) * (32768 / 8) + (bid >> 3);

    int oh = wg & 63;
    int c  = (wg >> 6) & 31;
    int n  = wg >> 11;

    int tid = threadIdx.x;
    int q   = tid & 15;   // quad: pixels x = 4q .. 4q+3
    int g   = tid >> 4;   // group 0..15

    // ---- Stage this row's weights: wlds[kk][col] = wt[n][c][kk][oh*64+col].
    const float* wbase = wt + ((size_t)(n * CW + c) * 9) * PIX + oh * HW;
    if (tid < 144) {
        int f   = tid * 4;        // flat index into [9][64]
        int kk  = f >> 6;
        int col = f & 63;
        float4 v = *(const float4*)(wbase + (size_t)kk * PIX + col);
        *(float4*)(&wlds[kk][col]) = v;
    }
    __syncthreads();

    int x = q * 4;

    // Zero-pad masks. q==0 / q==15 also kill cross-group shuffle garbage.
    float mt = (oh == 0)  ? 0.f : 1.f;
    float mb = (oh == 63) ? 0.f : 1.f;
    float ml = (q == 0)   ? 0.f : 1.f;
    float mr = (q == 15)  ? 0.f : 1.f;
    float mlt = ml * mt, mrt = mr * mt, mlb = ml * mb, mrb = mr * mb;

    const int r0 = (oh == 0  ? 0  : oh - 1) * HW;
    const int r1 = oh * HW;
    const int r2 = (oh == 63 ? 63 : oh + 1) * HW;

    const float* ip = in + ((size_t)(n * CX) + (size_t)(g * CW + c)) * PIX;

    float4 q0 = *(const float4*)(ip + r0 + x);
    float4 q1 = *(const float4*)(ip + r1 + x);
    float4 q2 = *(const float4*)(ip + r2 + x);

    // Halo pixels from neighbor lanes (garbage at q==0/15 masked below).
    float l0 = __shfl_up(q0.w, 1), h0 = __shfl_down(q0.x, 1);
    float l1 = __shfl_up(q1.w, 1), h1 = __shfl_down(q1.x, 1);
    float l2 = __shfl_up(q2.w, 1), h2 = __shfl_down(q2.x, 1);

    // Mask the inputs (cheaper than masking 9 float4 weights).
    q0.x *= mt; q0.y *= mt; q0.z *= mt; q0.w *= mt;
    q2.x *= mb; q2.y *= mb; q2.z *= mb; q2.w *= mb;
    l0 *= mlt; h0 *= mrt;
    l1 *= ml;  h1 *= mr;
    l2 *= mlb; h2 *= mrb;

    float4 w0 = *(const float4*)&wlds[0][x];
    float4 w1 = *(const float4*)&wlds[1][x];
    float4 w2 = *(const float4*)&wlds[2][x];
    float4 w3 = *(const float4*)&wlds[3][x];
    float4 w4 = *(const float4*)&wlds[4][x];
    float4 w5 = *(const float4*)&wlds[5][x];
    float4 w6 = *(const float4*)&wlds[6][x];
    float4 w7 = *(const float4*)&wlds[7][x];
    float4 w8 = *(const float4*)&wlds[8][x];

    float4 acc;
    acc.x = w0.x * l0;
    acc.y = w0.y * q0.x;
    acc.z = w0.z * q0.y;
    acc.w = w0.w * q0.z;

    acc.x = fmaf(w1.x, q0.x, acc.x);
    acc.y = fmaf(w1.y, q0.y, acc.y);
    acc.z = fmaf(w1.z, q0.z, acc.z);
    acc.w = fmaf(w1.w, q0.w, acc.w);

    acc.x = fmaf(w2.x, q0.y, acc.x);
    acc.y = fmaf(w2.y, q0.z, acc.y);
    acc.z = fmaf(w2.z, q0.w, acc.z);
    acc.w = fmaf(w2.w, h0,   acc.w);

    acc.x = fmaf(w3.x, l1,   acc.x);
    acc.y = fmaf(w3.y, q1.x, acc.y);
    acc.z = fmaf(w3.z, q1.y, acc.z);
    acc.w = fmaf(w3.w, q1.z, acc.w);

    acc.x = fmaf(w4.x, q1.x, acc.x);
    acc.y = fmaf(w4.y, q1.y, acc.y);
    acc.z = fmaf(w4.z, q1.z, acc.z);
    acc.w = fmaf(w4.w, q1.w, acc.w);

    acc.x = fmaf(w5.x, q1.y, acc.x);
    acc.y = fmaf(w5.y, q1.z, acc.y);
    acc.z = fmaf(w5.z, q1.w, acc.z);
    acc.w = fmaf(w5.w, h1,   acc.w);

    acc.x = fmaf(w6.x, l2,   acc.x);
    acc.y = fmaf(w6.y, q2.x, acc.y);
    acc.z = fmaf(w6.z, q2.y, acc.z);
    acc.w = fmaf(w6.w, q2.z, acc.w);

    acc.x = fmaf(w7.x, q2.x, acc.x);
    acc.y = fmaf(w7.y, q2.y, acc.y);
    acc.z = fmaf(w7.z, q2.z, acc.z);
    acc.w = fmaf(w7.w, q2.w, acc.w);

    acc.x = fmaf(w8.x, q2.y, acc.x);
    acc.y = fmaf(w8.y, q2.z, acc.y);
    acc.z = fmaf(w8.z, q2.w, acc.z);
    acc.w = fmaf(w8.w, h2,   acc.w);

    float* op = out + ((size_t)(n * CX) + (size_t)(g * CW + c)) * PIX + r1 + x;
    *(float4*)op = acc;
}

extern "C" void kernel_launch(void* const* d_in, const int* in_sizes, int n_in,
                              void* d_out, int out_size, void* d_ws, size_t ws_size,
                              hipStream_t stream) {
    const float* in = (const float*)d_in[0];   // (16, 512, 64, 64) f32
    const float* wt = (const float*)d_in[1];   // (16, 32, 9, 4096) f32
    float* out = (float*)d_out;                // (16, 512, 64, 64) f32

    const int grid  = NB * CW * HW;   // 32768 blocks
    const int block = 256;            // 16 groups x 16 quads
    agg_kernel<<<grid, block, 0, stream>>>(in, wt, out);
}

// Round 8
// 53.419 us; speedup vs baseline: 1.8014x; 1.3897x over previous
//
#include <hip/hip_runtime.h>

// N=16, C_X=512, C_W=32, groups=16, H=W=out_h=out_w=64, K=3, PAD=1.
constexpr int NB   = 16;
constexpr int CX   = 512;
constexpr int CW   = 32;
constexpr int GRP  = 16;   // CX / CW
constexpr int HW   = 64;
constexpr int PIX  = HW * HW; // 4096

// Native vector type for nontemporal builtin (HIP float4 is a class type).
typedef float f32x4 __attribute__((ext_vector_type(4)));

// One-shot threads, float4 width: thread <-> (n, c, g, oh, quad of 4 ow).
// Block = 256 threads = one (n,c,oh) row x all 16 groups x 16 quads.
// Output stores are NON-TEMPORAL: output is write-once, keeping it out of
// L2/L3 lets input+weight (209 MB) stay L3-resident (256 MiB).
__global__ __launch_bounds__(256, 8) void agg_kernel(
    const float* __restrict__ in,   // [16][512][64][64]
    const float* __restrict__ wt,   // [16][32][9][4096]
    float* __restrict__ out)        // [16][512][64][64]
{
    __shared__ float wlds[9][64];

    // Chunked XCD swizzle: 32768 blocks, bijective (32768 % 8 == 0).
    int bid = blockIdx.x;
    int wg  = (bid & 7) * (32768 / 8) + (bid >> 3);

    int oh = wg & 63;
    int c  = (wg >> 6) & 31;
    int n  = wg >> 11;

    int tid = threadIdx.x;
    int q   = tid & 15;   // quad: pixels x = 4q .. 4q+3
    int g   = tid >> 4;   // group 0..15

    // ---- Stage this row's weights: wlds[kk][col] = wt[n][c][kk][oh*64+col].
    const float* wbase = wt + ((size_t)(n * CW + c) * 9) * PIX + oh * HW;
    if (tid < 144) {
        int f   = tid * 4;        // flat index into [9][64]
        int kk  = f >> 6;
        int col = f & 63;
        float4 v = *(const float4*)(wbase + (size_t)kk * PIX + col);
        *(float4*)(&wlds[kk][col]) = v;
    }
    __syncthreads();

    int x = q * 4;

    // Zero-pad masks. q==0 / q==15 also kill cross-group shuffle garbage.
    float mt = (oh == 0)  ? 0.f : 1.f;
    float mb = (oh == 63) ? 0.f : 1.f;
    float ml = (q == 0)   ? 0.f : 1.f;
    float mr = (q == 15)  ? 0.f : 1.f;
    float mlt = ml * mt, mrt = mr * mt, mlb = ml * mb, mrb = mr * mb;

    const int r0 = (oh == 0  ? 0  : oh - 1) * HW;
    const int r1 = oh * HW;
    const int r2 = (oh == 63 ? 63 : oh + 1) * HW;

    const float* ip = in + ((size_t)(n * CX) + (size_t)(g * CW + c)) * PIX;

    float4 q0 = *(const float4*)(ip + r0 + x);
    float4 q1 = *(const float4*)(ip + r1 + x);
    float4 q2 = *(const float4*)(ip + r2 + x);

    // Halo pixels from neighbor lanes (garbage at q==0/15 masked below).
    float l0 = __shfl_up(q0.w, 1), h0 = __shfl_down(q0.x, 1);
    float l1 = __shfl_up(q1.w, 1), h1 = __shfl_down(q1.x, 1);
    float l2 = __shfl_up(q2.w, 1), h2 = __shfl_down(q2.x, 1);

    // Mask the inputs (cheaper than masking 9 float4 weights).
    q0.x *= mt; q0.y *= mt; q0.z *= mt; q0.w *= mt;
    q2.x *= mb; q2.y *= mb; q2.z *= mb; q2.w *= mb;
    l0 *= mlt; h0 *= mrt;
    l1 *= ml;  h1 *= mr;
    l2 *= mlb; h2 *= mrb;

    float4 w0 = *(const float4*)&wlds[0][x];
    float4 w1 = *(const float4*)&wlds[1][x];
    float4 w2 = *(const float4*)&wlds[2][x];
    float4 w3 = *(const float4*)&wlds[3][x];
    float4 w4 = *(const float4*)&wlds[4][x];
    float4 w5 = *(const float4*)&wlds[5][x];
    float4 w6 = *(const float4*)&wlds[6][x];
    float4 w7 = *(const float4*)&wlds[7][x];
    float4 w8 = *(const float4*)&wlds[8][x];

    float4 acc;
    acc.x = w0.x * l0;
    acc.y = w0.y * q0.x;
    acc.z = w0.z * q0.y;
    acc.w = w0.w * q0.z;

    acc.x = fmaf(w1.x, q0.x, acc.x);
    acc.y = fmaf(w1.y, q0.y, acc.y);
    acc.z = fmaf(w1.z, q0.z, acc.z);
    acc.w = fmaf(w1.w, q0.w, acc.w);

    acc.x = fmaf(w2.x, q0.y, acc.x);
    acc.y = fmaf(w2.y, q0.z, acc.y);
    acc.z = fmaf(w2.z, q0.w, acc.z);
    acc.w = fmaf(w2.w, h0,   acc.w);

    acc.x = fmaf(w3.x, l1,   acc.x);
    acc.y = fmaf(w3.y, q1.x, acc.y);
    acc.z = fmaf(w3.z, q1.y, acc.z);
    acc.w = fmaf(w3.w, q1.z, acc.w);

    acc.x = fmaf(w4.x, q1.x, acc.x);
    acc.y = fmaf(w4.y, q1.y, acc.y);
    acc.z = fmaf(w4.z, q1.z, acc.z);
    acc.w = fmaf(w4.w, q1.w, acc.w);

    acc.x = fmaf(w5.x, q1.y, acc.x);
    acc.y = fmaf(w5.y, q1.z, acc.y);
    acc.z = fmaf(w5.z, q1.w, acc.z);
    acc.w = fmaf(w5.w, h1,   acc.w);

    acc.x = fmaf(w6.x, l2,   acc.x);
    acc.y = fmaf(w6.y, q2.x, acc.y);
    acc.z = fmaf(w6.z, q2.y, acc.z);
    acc.w = fmaf(w6.w, q2.z, acc.w);

    acc.x = fmaf(w7.x, q2.x, acc.x);
    acc.y = fmaf(w7.y, q2.y, acc.y);
    acc.z = fmaf(w7.z, q2.z, acc.z);
    acc.w = fmaf(w7.w, q2.w, acc.w);

    acc.x = fmaf(w8.x, q2.y, acc.x);
    acc.y = fmaf(w8.y, q2.z, acc.y);
    acc.z = fmaf(w8.z, q2.w, acc.z);
    acc.w = fmaf(w8.w, h2,   acc.w);

    float* op = out + ((size_t)(n * CX) + (size_t)(g * CW + c)) * PIX + r1 + x;
    f32x4 nv = { acc.x, acc.y, acc.z, acc.w };
    __builtin_nontemporal_store(nv, (f32x4*)op);
}

extern "C" void kernel_launch(void* const* d_in, const int* in_sizes, int n_in,
                              void* d_out, int out_size, void* d_ws, size_t ws_size,
                              hipStream_t stream) {
    const float* in = (const float*)d_in[0];   // (16, 512, 64, 64) f32
    const float* wt = (const float*)d_in[1];   // (16, 32, 9, 4096) f32
    float* out = (float*)d_out;                // (16, 512, 64, 64) f32

    const int grid  = NB * CW * HW;   // 32768 blocks
    const int block = 256;            // 16 groups x 16 quads
    agg_kernel<<<grid, block, 0, stream>>>(in, wt, out);
}